// Round 1
// 254.259 us; speedup vs baseline: 1.1035x; 1.1035x over previous
//
#include <hip/hip_runtime.h>

#define T_LEN  16384
#define LTAG   64
#define F_PER  14
#define NCHUNK 1024        // chunks of 16 -> 4 blocks/CU -> all 4 SIMDs busy
#define CHUNK  16
#define BOS_ID 0
#define EOS_ID 1
#define NREG   6
#define REGSZ  833334      // 6 x 833334 >= 5,000,000 ; 3.33 MB/region (L2-resident)
#define WARM   64          // forward warm-up (coalescence ~10-30; extra margin at 1024 boundaries)
#define WB     96          // backward warm-up for bp backtrack coalescence

typedef __attribute__((ext_vector_type(4))) int i4;

// workspace layout (bytes)
static constexpr size_t EM_OFF = 0;                                 // float[T*64] 4 MB
static constexpr size_t BP_OFF = EM_OFF + (size_t)T_LEN * 64 * 4;   // uchar[T*64] 1 MB
static constexpr size_t AE_OFF = BP_OFF + (size_t)T_LEN * 64;       // float[64]
static constexpr size_t PS_OFF = AE_OFF + 512;                      // double[1024]

// ---------------------------------------------------------------------------
// K1: emissions  em[t,l] = sum_f w[feat[t,l,f]]  (fp32)
// Region-sweep gather; regions 10 -> 6 (3.33 MB each, still L2/XCD-resident)
// to cut the predicated-gather instruction amplification ~40%.
// ---------------------------------------------------------------------------
__global__ __launch_bounds__(256) void k_emissions(
    const int* __restrict__ idx, const float* __restrict__ w, float* __restrict__ em)
{
    __shared__ int sIdx[256 * F_PER];          // 14 KB
    const int tid = threadIdx.x;
    const int* g = idx + (size_t)blockIdx.x * (256 * F_PER);
    for (int x = tid * 4; x < 256 * F_PER; x += 1024)
        *(i4*)(sIdx + x) = __builtin_nontemporal_load((const i4*)(g + x));
    __syncthreads();
    int id[F_PER];
#pragma unroll
    for (int f = 0; f < F_PER; ++f) id[f] = sIdx[tid * F_PER + f];
    float sf[F_PER];
#pragma unroll
    for (int f = 0; f < F_PER; ++f) sf[f] = 0.f;
    for (int r = 0; r < NREG; ++r) {
        const int lo = r * REGSZ;
#pragma unroll
        for (int f = 0; f < F_PER; ++f)
            if ((unsigned)(id[f] - lo) < (unsigned)REGSZ) sf[f] += w[id[f]];
    }
    float s = 0.f;
#pragma unroll
    for (int f = 0; f < F_PER; f += 2) s += sf[f] + sf[f + 1];
    em[(size_t)blockIdx.x * 256 + tid] = s;
}

// ---------------------------------------------------------------------------
// K2: forward Viterbi with self-warm. 1024 chunks of 16 real steps.
// T column in 64 VGPRs (no LDS in inner loop for T); alpha broadcast via
// 1 ds_write + 16 uniform ds_read_b128; em prefetched one step ahead.
// Chunks with t0 <= WARM start EXACT from t=0. Last chunk exports alpha(16383).
// ---------------------------------------------------------------------------
__global__ __launch_bounds__(64) void k_phase3(
    const float* __restrict__ trans, const float* __restrict__ em,
    unsigned char* __restrict__ bp, float* __restrict__ aEnd)
{
    __shared__ __align__(16) float sa[64];
    const int c = blockIdx.x;
    const int tid = threadIdx.x;                 // = state j
    const int t0 = c * CHUNK;
    int nsteps = (T_LEN - 1) - t0; if (nsteps > CHUNK) nsteps = CHUNK;

    float tr_[64];                               // T[i][tid], i = 0..63
#pragma unroll
    for (int i = 0; i < 64; ++i) tr_[i] = trans[i * 64 + tid];

    float a; int tw;
    if (t0 <= WARM) { tw = 0; a = tr_[BOS_ID] + em[tid]; }   // exact init at t=0
    else            { tw = t0 - WARM; a = em[(size_t)tw * 64 + tid]; } // neutral init

    float e_nxt = em[(size_t)(tw + 1) * 64 + tid];

    // warm (or exact-replay) steps: no backpointers
    for (int t = tw + 1; t <= t0; ++t) {
        const float e = e_nxt;
        e_nxt = em[(size_t)(t + 1) * 64 + tid];
        sa[tid] = a;
        float m = -3.0e38f;
        const float4* ap = (const float4*)sa;
#pragma unroll
        for (int q = 0; q < 16; ++q) {
            float4 av = ap[q];                   // uniform-addr broadcast read
            m = fmaxf(m, fmaxf(fmaxf(tr_[4*q]   + av.x, tr_[4*q+1] + av.y),
                               fmaxf(tr_[4*q+2] + av.z, tr_[4*q+3] + av.w)));
        }
        a = e + m;
    }

    // real steps: emit backpointers (strict > keeps FIRST max = jnp.argmax)
    const int tend = t0 + nsteps;
    for (int t = t0 + 1; t <= tend; ++t) {
        const float e = e_nxt;
        const int tn = (t + 1 <= T_LEN - 1) ? t + 1 : T_LEN - 1;
        e_nxt = em[(size_t)tn * 64 + tid];
        sa[tid] = a;
        float m = -3.0e38f; int bi = 0;
        const float4* ap = (const float4*)sa;
#pragma unroll
        for (int q = 0; q < 16; ++q) {
            float4 av = ap[q];
            float v;
            v = tr_[4*q]   + av.x; if (v > m) { m = v; bi = 4*q;   }
            v = tr_[4*q+1] + av.y; if (v > m) { m = v; bi = 4*q+1; }
            v = tr_[4*q+2] + av.z; if (v > m) { m = v; bi = 4*q+2; }
            v = tr_[4*q+3] + av.w; if (v > m) { m = v; bi = 4*q+3; }
        }
        a = e + m;
        bp[(size_t)t * 64 + tid] = (unsigned char)bi;
    }
    if (c == NCHUNK - 1) aEnd[tid] = a;          // alpha at t = 16383
}

// ---------------------------------------------------------------------------
// K3: per-chunk warm backtrack -> path + EXACT fp64 score terms.
// bp maps coalesce under composition (same phenomenon as the forward warm):
// start WB steps past the chunk end with an arbitrary tag; by the chunk end
// the walked tag equals the true path tag. Tail blocks whose window reaches
// t=16383 start from the EXACT final tag (argmax of aEnd + T[:,EOS]).
// Replaces gmap + serial map composition + k_path_score.
// ---------------------------------------------------------------------------
__global__ __launch_bounds__(64) void k_backtrack(
    const float* __restrict__ trans, const float* __restrict__ em,
    const unsigned char* __restrict__ bp, const float* __restrict__ aEnd,
    float* __restrict__ out, double* __restrict__ partial)
{
    __shared__ __align__(16) unsigned char sbp[(CHUNK + WB) * 64];   // 7 KB
    const int c = blockIdx.x;
    const int tid = threadIdx.x;
    const int t0 = c * CHUNK;
    int nsteps = (T_LEN - 1) - t0; if (nsteps > CHUNK) nsteps = CHUNK;
    int t_hi = t0 + nsteps + WB; if (t_hi > T_LEN - 1) t_hi = T_LEN - 1;
    const int nrows = t_hi - t0;                 // bp rows t0+1 .. t_hi

    // stage bp window into LDS (coalesced 16B loads; nrows*64 is a mult of 64)
    const unsigned char* gsrc = bp + (size_t)(t0 + 1) * 64;
    for (int x = tid * 16; x < nrows * 64; x += 1024)
        *(i4*)(sbp + x) = *(const i4*)(gsrc + x);

    // final tag: argmax_j aEnd[j] + T[j][EOS], first-occurrence tie-break
    float val = aEnd[tid] + trans[tid * 64 + EOS_ID];
    int idx = tid;
#pragma unroll
    for (int o = 32; o >= 1; o >>= 1) {
        float ov = __shfl_xor(val, o);
        int   oi = __shfl_xor(idx, o);
        if (ov > val || (ov == val && oi < idx)) { val = ov; idx = oi; }
    }
    __syncthreads();

    // walk down; all lanes follow the same tag (broadcast LDS reads).
    // Lane tid captures pp = tag(t0+tid), pt = tag(t0+tid+1).
    int tag = (t_hi == T_LEN - 1) ? idx : 0;
    int pp = 0, pt = 0;
    for (int t = t_hi; t > t0; --t) {
        const int r = t - t0;
        if (tid == r)     pp = tag;
        if (tid + 1 == r) pt = tag;
        tag = sbp[(r - 1) * 64 + tag];
    }
    if (tid == 0) pp = tag;                      // tag at t0

    // path writes (chunk c owns path[t0 .. t0+nsteps-1]; last chunk adds t=16383)
    if (tid < nsteps) out[1 + t0 + tid] = (float)pp;
    if (c == NCHUNK - 1 && tid == nsteps) out[1 + (T_LEN - 1)] = (float)pp;

    // exact fp64 score terms for t in (t0, t0+nsteps]
    double term = 0.0;
    if (tid < nsteps) {
        const int t = t0 + 1 + tid;
        term = (double)trans[pp * 64 + pt] + (double)em[(size_t)t * 64 + pt];
    }
    if (c == 0 && tid == 0)
        term += (double)trans[BOS_ID * 64 + pp] + (double)em[pp];
    if (c == NCHUNK - 1 && tid == nsteps)
        term += (double)trans[pp * 64 + EOS_ID];
#pragma unroll
    for (int o = 1; o < 64; o <<= 1) term += __shfl_xor(term, o);
    if (tid == 0) partial[c] = term;
}

// ---------------------------------------------------------------------------
// K4: reduce 1024 partials -> out[0]
// ---------------------------------------------------------------------------
__global__ __launch_bounds__(64) void k_sfin(
    const double* __restrict__ partial, float* __restrict__ out)
{
    const int tid = threadIdx.x;
    double s = 0.0;
    for (int k = tid; k < NCHUNK; k += 64) s += partial[k];
#pragma unroll
    for (int o = 1; o < 64; o <<= 1) s += __shfl_xor(s, o);
    if (tid == 0) out[0] = (float)s;
}

// ---------------------------------------------------------------------------
extern "C" void kernel_launch(void* const* d_in, const int* in_sizes, int n_in,
                              void* d_out, int out_size, void* d_ws, size_t ws_size,
                              hipStream_t stream)
{
    const int*   feat = (const int*)d_in[0];
    const float* w    = (const float*)d_in[1];
    const float* tr   = (const float*)d_in[2];
    float* out = (float*)d_out;
    char*  ws  = (char*)d_ws;

    float*         em = (float*)(ws + EM_OFF);
    unsigned char* bp = (unsigned char*)(ws + BP_OFF);
    float*         ae = (float*)(ws + AE_OFF);
    double*        ps = (double*)(ws + PS_OFF);

    k_emissions <<<(T_LEN * LTAG) / 256, 256, 0, stream>>>(feat, w, em);
    k_phase3    <<<NCHUNK, 64, 0, stream>>>(tr, em, bp, ae);
    k_backtrack <<<NCHUNK, 64, 0, stream>>>(tr, em, bp, ae, out, ps);
    k_sfin      <<<1,      64, 0, stream>>>(ps, out);
}

// Round 2
// 253.135 us; speedup vs baseline: 1.1084x; 1.0044x over previous
//
#include <hip/hip_runtime.h>

#define T_LEN  16384
#define LTAG   64
#define F_PER  14
#define NCHUNK 1024        // chunks of 16 -> 4 blocks/CU -> all 4 SIMDs busy
#define CHUNK  16
#define BOS_ID 0
#define EOS_ID 1
#define NREG   3
#define REGSZ  1666667     // 3 x 1666667 >= 5,000,000 ; 6.67 MB/region (L3-backed)
#define WARM   48          // forward warm-up (proven at round-0 boundaries)
#define WB     96          // backward warm-up for bp backtrack coalescence

typedef __attribute__((ext_vector_type(4))) int i4;

// workspace layout (bytes)
static constexpr size_t EM_OFF = 0;                                 // float[T*64] 4 MB
static constexpr size_t BP_OFF = EM_OFF + (size_t)T_LEN * 64 * 4;   // uchar[T*64] 1 MB
static constexpr size_t AE_OFF = BP_OFF + (size_t)T_LEN * 64;       // float[64]
static constexpr size_t PS_OFF = AE_OFF + 512;                      // double[1024]

// ---------------------------------------------------------------------------
// K1: emissions  em[t,l] = sum_f w[feat[t,l,f]]  (fp32)
// Region-sweep gather; 3 regions of 6.67 MB. Fewer gather instructions
// (TA/issue-bound per the NREG 10->6 measurement); extra L2 misses are
// absorbed by L3 (w = 20 MB << 256 MB).
// ---------------------------------------------------------------------------
__global__ __launch_bounds__(256) void k_emissions(
    const int* __restrict__ idx, const float* __restrict__ w, float* __restrict__ em)
{
    __shared__ int sIdx[256 * F_PER];          // 14 KB
    const int tid = threadIdx.x;
    const int* g = idx + (size_t)blockIdx.x * (256 * F_PER);
    for (int x = tid * 4; x < 256 * F_PER; x += 1024)
        *(i4*)(sIdx + x) = __builtin_nontemporal_load((const i4*)(g + x));
    __syncthreads();
    int id[F_PER];
#pragma unroll
    for (int f = 0; f < F_PER; ++f) id[f] = sIdx[tid * F_PER + f];
    float sf[F_PER];
#pragma unroll
    for (int f = 0; f < F_PER; ++f) sf[f] = 0.f;
    for (int r = 0; r < NREG; ++r) {
        const int lo = r * REGSZ;
#pragma unroll
        for (int f = 0; f < F_PER; ++f)
            if ((unsigned)(id[f] - lo) < (unsigned)REGSZ) sf[f] += w[id[f]];
    }
    float s = 0.f;
#pragma unroll
    for (int f = 0; f < F_PER; f += 2) s += sf[f] + sf[f + 1];
    em[(size_t)blockIdx.x * 256 + tid] = s;
}

// ---------------------------------------------------------------------------
// K2: forward Viterbi with self-warm. 1024 chunks of 16 real steps.
// T column in 64 VGPRs. Alpha broadcast: 1 ds_write + 16 ds_read_b128
// BATCHED into a register array vv[16] (single lgkmcnt drain) -- the
// previous version consumed each read inside the running-max chain, which
// serialized 16 LDS latencies per step. Reduction is a pure fmax tree;
// argmax = tree-max + descending equality scan (first max wins).
// ---------------------------------------------------------------------------
__global__ __launch_bounds__(64) void k_phase3(
    const float* __restrict__ trans, const float* __restrict__ em,
    unsigned char* __restrict__ bp, float* __restrict__ aEnd)
{
    __shared__ __align__(16) float sa[64];
    const int c = blockIdx.x;
    const int tid = threadIdx.x;                 // = state j
    const int t0 = c * CHUNK;
    int nsteps = (T_LEN - 1) - t0; if (nsteps > CHUNK) nsteps = CHUNK;

    float tr_[64];                               // T[i][tid], i = 0..63
#pragma unroll
    for (int i = 0; i < 64; ++i) tr_[i] = trans[i * 64 + tid];

    float a; int tw;
    if (t0 <= WARM) { tw = 0; a = tr_[BOS_ID] + em[tid]; }   // exact init at t=0
    else            { tw = t0 - WARM; a = em[(size_t)tw * 64 + tid]; } // neutral init

    float e_nxt = em[(size_t)(tw + 1) * 64 + tid];
    const float4* ap = (const float4*)sa;

    // warm (or exact-replay) steps: no backpointers
    for (int t = tw + 1; t <= t0; ++t) {
        const float e = e_nxt;
        e_nxt = em[(size_t)(t + 1) * 64 + tid];
        sa[tid] = a;
        float4 vv[16];
#pragma unroll
        for (int q = 0; q < 16; ++q) vv[q] = ap[q];          // 16 batched b128 reads
        float t8[16];
#pragma unroll
        for (int q = 0; q < 16; ++q) {
            const float x = tr_[4*q]   + vv[q].x;
            const float y = tr_[4*q+1] + vv[q].y;
            const float z = tr_[4*q+2] + vv[q].z;
            const float w = tr_[4*q+3] + vv[q].w;
            t8[q] = fmaxf(fmaxf(x, y), fmaxf(z, w));
        }
#pragma unroll
        for (int s = 8; s >= 1; s >>= 1)
#pragma unroll
            for (int i = 0; i < s; ++i) t8[i] = fmaxf(t8[i], t8[i + s]);
        a = e + t8[0];
    }

    // real steps: emit backpointers (first-max semantics = jnp.argmax)
    const int tend = t0 + nsteps;
    for (int t = t0 + 1; t <= tend; ++t) {
        const float e = e_nxt;
        const int tn = (t + 1 <= T_LEN - 1) ? t + 1 : T_LEN - 1;
        e_nxt = em[(size_t)tn * 64 + tid];
        sa[tid] = a;
        float4 vv[16];
#pragma unroll
        for (int q = 0; q < 16; ++q) vv[q] = ap[q];          // batched reads
#pragma unroll
        for (int q = 0; q < 16; ++q) {
            vv[q].x += tr_[4*q];
            vv[q].y += tr_[4*q+1];
            vv[q].z += tr_[4*q+2];
            vv[q].w += tr_[4*q+3];
        }
        float t8[16];
#pragma unroll
        for (int q = 0; q < 16; ++q)
            t8[q] = fmaxf(fmaxf(vv[q].x, vv[q].y), fmaxf(vv[q].z, vv[q].w));
#pragma unroll
        for (int s = 8; s >= 1; s >>= 1)
#pragma unroll
            for (int i = 0; i < s; ++i) t8[i] = fmaxf(t8[i], t8[i + s]);
        const float m = t8[0];
        // descending equality scan -> smallest index attaining m
        int bi = 63;
#pragma unroll
        for (int q = 15; q >= 0; --q) {
            bi = (vv[q].w == m) ? 4*q+3 : bi;
            bi = (vv[q].z == m) ? 4*q+2 : bi;
            bi = (vv[q].y == m) ? 4*q+1 : bi;
            bi = (vv[q].x == m) ? 4*q   : bi;
        }
        a = e + m;
        bp[(size_t)t * 64 + tid] = (unsigned char)bi;
    }
    if (c == NCHUNK - 1) aEnd[tid] = a;          // alpha at t = 16383
}

// ---------------------------------------------------------------------------
// K3: per-chunk warm backtrack -> path + EXACT fp64 score terms.
// ---------------------------------------------------------------------------
__global__ __launch_bounds__(64) void k_backtrack(
    const float* __restrict__ trans, const float* __restrict__ em,
    const unsigned char* __restrict__ bp, const float* __restrict__ aEnd,
    float* __restrict__ out, double* __restrict__ partial)
{
    __shared__ __align__(16) unsigned char sbp[(CHUNK + WB) * 64];   // 7 KB
    const int c = blockIdx.x;
    const int tid = threadIdx.x;
    const int t0 = c * CHUNK;
    int nsteps = (T_LEN - 1) - t0; if (nsteps > CHUNK) nsteps = CHUNK;
    int t_hi = t0 + nsteps + WB; if (t_hi > T_LEN - 1) t_hi = T_LEN - 1;
    const int nrows = t_hi - t0;                 // bp rows t0+1 .. t_hi

    // stage bp window into LDS (coalesced 16B loads)
    const unsigned char* gsrc = bp + (size_t)(t0 + 1) * 64;
    for (int x = tid * 16; x < nrows * 64; x += 1024)
        *(i4*)(sbp + x) = *(const i4*)(gsrc + x);

    // final tag: argmax_j aEnd[j] + T[j][EOS], first-occurrence tie-break
    float val = aEnd[tid] + trans[tid * 64 + EOS_ID];
    int idx = tid;
#pragma unroll
    for (int o = 32; o >= 1; o >>= 1) {
        float ov = __shfl_xor(val, o);
        int   oi = __shfl_xor(idx, o);
        if (ov > val || (ov == val && oi < idx)) { val = ov; idx = oi; }
    }
    __syncthreads();

    // walk down; all lanes follow the same tag (broadcast LDS reads).
    int tag = (t_hi == T_LEN - 1) ? idx : 0;
    int pp = 0, pt = 0;
    for (int t = t_hi; t > t0; --t) {
        const int r = t - t0;
        if (tid == r)     pp = tag;
        if (tid + 1 == r) pt = tag;
        tag = sbp[(r - 1) * 64 + tag];
    }
    if (tid == 0) pp = tag;                      // tag at t0

    // path writes
    if (tid < nsteps) out[1 + t0 + tid] = (float)pp;
    if (c == NCHUNK - 1 && tid == nsteps) out[1 + (T_LEN - 1)] = (float)pp;

    // exact fp64 score terms for t in (t0, t0+nsteps]
    double term = 0.0;
    if (tid < nsteps) {
        const int t = t0 + 1 + tid;
        term = (double)trans[pp * 64 + pt] + (double)em[(size_t)t * 64 + pt];
    }
    if (c == 0 && tid == 0)
        term += (double)trans[BOS_ID * 64 + pp] + (double)em[pp];
    if (c == NCHUNK - 1 && tid == nsteps)
        term += (double)trans[pp * 64 + EOS_ID];
#pragma unroll
    for (int o = 1; o < 64; o <<= 1) term += __shfl_xor(term, o);
    if (tid == 0) partial[c] = term;
}

// ---------------------------------------------------------------------------
// K4: reduce 1024 partials -> out[0]
// ---------------------------------------------------------------------------
__global__ __launch_bounds__(64) void k_sfin(
    const double* __restrict__ partial, float* __restrict__ out)
{
    const int tid = threadIdx.x;
    double s = 0.0;
    for (int k = tid; k < NCHUNK; k += 64) s += partial[k];
#pragma unroll
    for (int o = 1; o < 64; o <<= 1) s += __shfl_xor(s, o);
    if (tid == 0) out[0] = (float)s;
}

// ---------------------------------------------------------------------------
extern "C" void kernel_launch(void* const* d_in, const int* in_sizes, int n_in,
                              void* d_out, int out_size, void* d_ws, size_t ws_size,
                              hipStream_t stream)
{
    const int*   feat = (const int*)d_in[0];
    const float* w    = (const float*)d_in[1];
    const float* tr   = (const float*)d_in[2];
    float* out = (float*)d_out;
    char*  ws  = (char*)d_ws;

    float*         em = (float*)(ws + EM_OFF);
    unsigned char* bp = (unsigned char*)(ws + BP_OFF);
    float*         ae = (float*)(ws + AE_OFF);
    double*        ps = (double*)(ws + PS_OFF);

    k_emissions <<<(T_LEN * LTAG) / 256, 256, 0, stream>>>(feat, w, em);
    k_phase3    <<<NCHUNK, 64, 0, stream>>>(tr, em, bp, ae);
    k_backtrack <<<NCHUNK, 64, 0, stream>>>(tr, em, bp, ae, out, ps);
    k_sfin      <<<1,      64, 0, stream>>>(ps, out);
}

// Round 3
// 225.999 us; speedup vs baseline: 1.2415x; 1.1201x over previous
//
#include <hip/hip_runtime.h>

#define T_LEN  16384
#define LTAG   64
#define F_PER  14
#define NCHUNK 1024        // chunks of 16 -> 4 blocks/CU
#define CHUNK  16
#define BOS_ID 0
#define EOS_ID 1
#define NREG   6
#define REGSZ  833334      // 6 x 833334 >= 5,000,000 ; 3.33 MB/region -> fits 4 MB per-XCD L2
#define WARM   48          // forward warm-up (proven)
#define WB     96          // backward warm-up for bp backtrack coalescence

typedef __attribute__((ext_vector_type(4))) int i4;

// workspace layout (bytes)
static constexpr size_t EM_OFF = 0;                                 // float[T*64] 4 MB
static constexpr size_t BP_OFF = EM_OFF + (size_t)T_LEN * 64 * 4;   // uchar[T*64] 1 MB
static constexpr size_t AE_OFF = BP_OFF + (size_t)T_LEN * 64;       // float[64]
static constexpr size_t PS_OFF = AE_OFF + 512;                      // double[1024]

// ---------------------------------------------------------------------------
// K1: emissions  em[t,l] = sum_f w[feat[t,l,f]]  (fp32)
// Region-sweep gather, NREG=6: 3.33 MB regions stay L2-resident (NREG=3's
// 6.67 MB regions overflowed the 4 MB per-XCD L2 and cost +30 us).
// ---------------------------------------------------------------------------
__global__ __launch_bounds__(256) void k_emissions(
    const int* __restrict__ idx, const float* __restrict__ w, float* __restrict__ em)
{
    __shared__ int sIdx[256 * F_PER];          // 14 KB
    const int tid = threadIdx.x;
    const int* g = idx + (size_t)blockIdx.x * (256 * F_PER);
    for (int x = tid * 4; x < 256 * F_PER; x += 1024)
        *(i4*)(sIdx + x) = __builtin_nontemporal_load((const i4*)(g + x));
    __syncthreads();
    int id[F_PER];
#pragma unroll
    for (int f = 0; f < F_PER; ++f) id[f] = sIdx[tid * F_PER + f];
    float sf[F_PER];
#pragma unroll
    for (int f = 0; f < F_PER; ++f) sf[f] = 0.f;
    for (int r = 0; r < NREG; ++r) {
        const int lo = r * REGSZ;
#pragma unroll
        for (int f = 0; f < F_PER; ++f)
            if ((unsigned)(id[f] - lo) < (unsigned)REGSZ) sf[f] += w[id[f]];
    }
    float s = 0.f;
#pragma unroll
    for (int f = 0; f < F_PER; f += 2) s += sf[f] + sf[f + 1];
    em[(size_t)blockIdx.x * 256 + tid] = s;
}

// ---------------------------------------------------------------------------
// K2: forward Viterbi with self-warm. 1024 chunks of 16 real steps.
// __launch_bounds__(64, 1): 1 wave/EU -> full 512-VGPR budget. Without the
// min-waves arg the backend may cap VGPRs for an occupancy target and spill
// tr_[64]/vv[] to scratch -- suspected cause of the 5x model-vs-measured gap.
// Step body processes source states in 4 groups of 16 (peak live ~110 regs):
// 4x ds_read_b128 -> 16 add -> tree-max(16) -> first-index scan(16) -> merge.
// ---------------------------------------------------------------------------
__global__ __launch_bounds__(64, 1) void k_phase3(
    const float* __restrict__ trans, const float* __restrict__ em,
    unsigned char* __restrict__ bp, float* __restrict__ aEnd)
{
    __shared__ __align__(16) float sa[64];
    const int c = blockIdx.x;
    const int tid = threadIdx.x;                 // = state j
    const int t0 = c * CHUNK;
    int nsteps = (T_LEN - 1) - t0; if (nsteps > CHUNK) nsteps = CHUNK;

    float tr_[64];                               // T[i][tid], i = 0..63
#pragma unroll
    for (int i = 0; i < 64; ++i) tr_[i] = trans[i * 64 + tid];

    float a; int tw;
    if (t0 <= WARM) { tw = 0; a = tr_[BOS_ID] + em[tid]; }   // exact init at t=0
    else            { tw = t0 - WARM; a = em[(size_t)tw * 64 + tid]; } // neutral init

    float e_nxt = em[(size_t)(tw + 1) * 64 + tid];
    const float4* ap = (const float4*)sa;

    // warm (or exact-replay) steps: no backpointers
    for (int t = tw + 1; t <= t0; ++t) {
        const float e = e_nxt;
        e_nxt = em[(size_t)(t + 1) * 64 + tid];
        sa[tid] = a;
        float m = -3.0e38f;
#pragma unroll
        for (int g = 0; g < 4; ++g) {
            const float4 v0 = ap[4*g+0], v1 = ap[4*g+1], v2 = ap[4*g+2], v3 = ap[4*g+3];
            float s0[16];
            s0[0]  = tr_[16*g+0]  + v0.x;  s0[1]  = tr_[16*g+1]  + v0.y;
            s0[2]  = tr_[16*g+2]  + v0.z;  s0[3]  = tr_[16*g+3]  + v0.w;
            s0[4]  = tr_[16*g+4]  + v1.x;  s0[5]  = tr_[16*g+5]  + v1.y;
            s0[6]  = tr_[16*g+6]  + v1.z;  s0[7]  = tr_[16*g+7]  + v1.w;
            s0[8]  = tr_[16*g+8]  + v2.x;  s0[9]  = tr_[16*g+9]  + v2.y;
            s0[10] = tr_[16*g+10] + v2.z;  s0[11] = tr_[16*g+11] + v2.w;
            s0[12] = tr_[16*g+12] + v3.x;  s0[13] = tr_[16*g+13] + v3.y;
            s0[14] = tr_[16*g+14] + v3.z;  s0[15] = tr_[16*g+15] + v3.w;
#pragma unroll
            for (int st = 8; st >= 1; st >>= 1)
#pragma unroll
                for (int i = 0; i < st; ++i) s0[i] = fmaxf(s0[i], s0[i + st]);
            m = fmaxf(m, s0[0]);
        }
        a = e + m;
    }

    // real steps: emit backpointers (first-max semantics = jnp.argmax)
    const int tend = t0 + nsteps;
    for (int t = t0 + 1; t <= tend; ++t) {
        const float e = e_nxt;
        const int tn = (t + 1 <= T_LEN - 1) ? t + 1 : T_LEN - 1;
        e_nxt = em[(size_t)tn * 64 + tid];
        sa[tid] = a;
        float m = -3.0e38f; int bi = 0;
#pragma unroll
        for (int g = 0; g < 4; ++g) {
            const float4 v0 = ap[4*g+0], v1 = ap[4*g+1], v2 = ap[4*g+2], v3 = ap[4*g+3];
            float s0[16];
            s0[0]  = tr_[16*g+0]  + v0.x;  s0[1]  = tr_[16*g+1]  + v0.y;
            s0[2]  = tr_[16*g+2]  + v0.z;  s0[3]  = tr_[16*g+3]  + v0.w;
            s0[4]  = tr_[16*g+4]  + v1.x;  s0[5]  = tr_[16*g+5]  + v1.y;
            s0[6]  = tr_[16*g+6]  + v1.z;  s0[7]  = tr_[16*g+7]  + v1.w;
            s0[8]  = tr_[16*g+8]  + v2.x;  s0[9]  = tr_[16*g+9]  + v2.y;
            s0[10] = tr_[16*g+10] + v2.z;  s0[11] = tr_[16*g+11] + v2.w;
            s0[12] = tr_[16*g+12] + v3.x;  s0[13] = tr_[16*g+13] + v3.y;
            s0[14] = tr_[16*g+14] + v3.z;  s0[15] = tr_[16*g+15] + v3.w;
            float t16[16];
#pragma unroll
            for (int i = 0; i < 16; ++i) t16[i] = s0[i];
#pragma unroll
            for (int st = 8; st >= 1; st >>= 1)
#pragma unroll
                for (int i = 0; i < st; ++i) t16[i] = fmaxf(t16[i], t16[i + st]);
            const float gm = t16[0];
            int gb = 15;                          // first index attaining gm
#pragma unroll
            for (int i = 14; i >= 0; --i) gb = (s0[i] == gm) ? i : gb;
            if (gm > m) { m = gm; bi = 16*g + gb; }   // strict > keeps first group
        }
        a = e + m;
        bp[(size_t)t * 64 + tid] = (unsigned char)bi;
    }
    if (c == NCHUNK - 1) aEnd[tid] = a;          // alpha at t = 16383
}

// ---------------------------------------------------------------------------
// K3: per-chunk warm backtrack -> path + EXACT fp64 score terms.
// ---------------------------------------------------------------------------
__global__ __launch_bounds__(64) void k_backtrack(
    const float* __restrict__ trans, const float* __restrict__ em,
    const unsigned char* __restrict__ bp, const float* __restrict__ aEnd,
    float* __restrict__ out, double* __restrict__ partial)
{
    __shared__ __align__(16) unsigned char sbp[(CHUNK + WB) * 64];   // 7 KB
    const int c = blockIdx.x;
    const int tid = threadIdx.x;
    const int t0 = c * CHUNK;
    int nsteps = (T_LEN - 1) - t0; if (nsteps > CHUNK) nsteps = CHUNK;
    int t_hi = t0 + nsteps + WB; if (t_hi > T_LEN - 1) t_hi = T_LEN - 1;
    const int nrows = t_hi - t0;                 // bp rows t0+1 .. t_hi

    // stage bp window into LDS (coalesced 16B loads)
    const unsigned char* gsrc = bp + (size_t)(t0 + 1) * 64;
    for (int x = tid * 16; x < nrows * 64; x += 1024)
        *(i4*)(sbp + x) = *(const i4*)(gsrc + x);

    // final tag: argmax_j aEnd[j] + T[j][EOS], first-occurrence tie-break
    float val = aEnd[tid] + trans[tid * 64 + EOS_ID];
    int idx = tid;
#pragma unroll
    for (int o = 32; o >= 1; o >>= 1) {
        float ov = __shfl_xor(val, o);
        int   oi = __shfl_xor(idx, o);
        if (ov > val || (ov == val && oi < idx)) { val = ov; idx = oi; }
    }
    __syncthreads();

    // walk down; all lanes follow the same tag (broadcast LDS reads).
    int tag = (t_hi == T_LEN - 1) ? idx : 0;
    int pp = 0, pt = 0;
    for (int t = t_hi; t > t0; --t) {
        const int r = t - t0;
        if (tid == r)     pp = tag;
        if (tid + 1 == r) pt = tag;
        tag = sbp[(r - 1) * 64 + tag];
    }
    if (tid == 0) pp = tag;                      // tag at t0

    // path writes
    if (tid < nsteps) out[1 + t0 + tid] = (float)pp;
    if (c == NCHUNK - 1 && tid == nsteps) out[1 + (T_LEN - 1)] = (float)pp;

    // exact fp64 score terms for t in (t0, t0+nsteps]
    double term = 0.0;
    if (tid < nsteps) {
        const int t = t0 + 1 + tid;
        term = (double)trans[pp * 64 + pt] + (double)em[(size_t)t * 64 + pt];
    }
    if (c == 0 && tid == 0)
        term += (double)trans[BOS_ID * 64 + pp] + (double)em[pp];
    if (c == NCHUNK - 1 && tid == nsteps)
        term += (double)trans[pp * 64 + EOS_ID];
#pragma unroll
    for (int o = 1; o < 64; o <<= 1) term += __shfl_xor(term, o);
    if (tid == 0) partial[c] = term;
}

// ---------------------------------------------------------------------------
// K4: reduce 1024 partials -> out[0]
// ---------------------------------------------------------------------------
__global__ __launch_bounds__(64) void k_sfin(
    const double* __restrict__ partial, float* __restrict__ out)
{
    const int tid = threadIdx.x;
    double s = 0.0;
    for (int k = tid; k < NCHUNK; k += 64) s += partial[k];
#pragma unroll
    for (int o = 1; o < 64; o <<= 1) s += __shfl_xor(s, o);
    if (tid == 0) out[0] = (float)s;
}

// ---------------------------------------------------------------------------
extern "C" void kernel_launch(void* const* d_in, const int* in_sizes, int n_in,
                              void* d_out, int out_size, void* d_ws, size_t ws_size,
                              hipStream_t stream)
{
    const int*   feat = (const int*)d_in[0];
    const float* w    = (const float*)d_in[1];
    const float* tr   = (const float*)d_in[2];
    float* out = (float*)d_out;
    char*  ws  = (char*)d_ws;

    float*         em = (float*)(ws + EM_OFF);
    unsigned char* bp = (unsigned char*)(ws + BP_OFF);
    float*         ae = (float*)(ws + AE_OFF);
    double*        ps = (double*)(ws + PS_OFF);

    k_emissions <<<(T_LEN * LTAG) / 256, 256, 0, stream>>>(feat, w, em);
    k_phase3    <<<NCHUNK, 64, 0, stream>>>(tr, em, bp, ae);
    k_backtrack <<<NCHUNK, 64, 0, stream>>>(tr, em, bp, ae, out, ps);
    k_sfin      <<<1,      64, 0, stream>>>(ps, out);
}